// Round 4
// baseline (95.066 us; speedup 1.0000x reference)
//
#include <hip/hip_runtime.h>

// WaveletTransformLayer: Haar DWT along sequence axis.
// x: (B=16, S=8192, C=512) fp32. out[b,s,c] = (x[b,2s,c]+x[b,2s+1,c])/sqrt2 ;
// out[b,S/2+s,c] = (x[b,2s,c]-x[b,2s+1,c])/sqrt2.
//
// Memory-bound (256 MiB in + 256 MiB out, streaming, zero reuse).
// R4: MLP probe — UNROLL 8 -> 16 (32 independent nt loads in flight per
// thread), block still owns one contiguous 4096-item run (32 s-rows of one
// b: 64 KB read run, 2x 32 KB write runs). If this is neutral vs R3's
// 91.8 us, the limiter is 3-stream DRAM turnaround -> practical roofline.
// 16*4096*128 = 8,388,608 items = 2048 blocks * 256 thr * 16 exactly.

typedef float f32x4 __attribute__((ext_vector_type(4)));

#define B_DIM 16
#define S_DIM 8192
#define C_DIM 512
#define C4 (C_DIM / 4)        // 128 float4 per row
#define SHALF (S_DIM / 2)     // 4096
#define UNROLL 16
#define NTHREADS 256
#define NBLOCKS 2048
#define BLOCK_ITEMS (NTHREADS * UNROLL)   // 4096

__global__ __launch_bounds__(NTHREADS) void wavelet_haar_kernel(
    const f32x4* __restrict__ x, f32x4* __restrict__ out) {
    const float r = 0.70710678118654752440f;

    // i in [0, 2^23): flattened (b, s, c4). Items: i += k*256 -> s += 2k.
    unsigned base = blockIdx.x * BLOCK_ITEMS + threadIdx.x;
    unsigned c4 = base & (C4 - 1);
    unsigned s  = (base >> 7) & (SHALF - 1);
    unsigned b  = base >> 19;

    long inE = ((long)b * S_DIM + 2 * s) * C4 + c4;  // even row, item 0
    long oA  = ((long)b * S_DIM + s) * C4 + c4;      // cA row, item 0
    long oD  = oA + (long)SHALF * C4;                // cD row, item 0
    const long IN_STRIDE  = 4L * C4;   // s += 2 -> even-row float4 idx += 512
    const long OUT_STRIDE = 2L * C4;   // s += 2 -> out float4 idx += 256

    f32x4 e[UNROLL], o[UNROLL];
#pragma unroll
    for (int k = 0; k < UNROLL; ++k) {
        e[k] = __builtin_nontemporal_load(x + inE + k * IN_STRIDE);
        o[k] = __builtin_nontemporal_load(x + inE + k * IN_STRIDE + C4);
    }
#pragma unroll
    for (int k = 0; k < UNROLL; ++k) {
        f32x4 a = (e[k] + o[k]) * r;
        f32x4 d = (e[k] - o[k]) * r;
        __builtin_nontemporal_store(a, out + oA + k * OUT_STRIDE);
        __builtin_nontemporal_store(d, out + oD + k * OUT_STRIDE);
    }
}

extern "C" void kernel_launch(void* const* d_in, const int* in_sizes, int n_in,
                              void* d_out, int out_size, void* d_ws, size_t ws_size,
                              hipStream_t stream) {
    const f32x4* x = (const f32x4*)d_in[0];
    f32x4* out = (f32x4*)d_out;
    wavelet_haar_kernel<<<NBLOCKS, NTHREADS, 0, stream>>>(x, out);
}

// Round 5
// 91.888 us; speedup vs baseline: 1.0346x; 1.0346x over previous
//
#include <hip/hip_runtime.h>

// WaveletTransformLayer: Haar DWT along sequence axis.
// x: (B=16, S=8192, C=512) fp32. out[b,s,c] = (x[b,2s,c]+x[b,2s+1,c])/sqrt2 ;
// out[b,S/2+s,c] = (x[b,2s,c]-x[b,2s+1,c])/sqrt2.
//
// Memory-bound (256 MiB in + 256 MiB out, streaming, zero reuse).
// FINAL (= R3, best: 91.8 us, 5.85 TB/s, 93% of copy ceiling).
// Flatten i over (b,s,c4); each block owns 2048 consecutive i (16 s-rows of
// one b, full c4), each thread owns 8 items at constant stride (s += 2).
// One address decomposition, 16 independent nontemporal float4 loads
// back-to-back, then compute + 16 nontemporal stores. Per block: one 32 KB
// contiguous read run, two 16 KB contiguous write runs.
// R4 probe showed UNROLL=16 regresses (95.1 us) -> MLP is saturated; the
// remaining 7% vs copy ceiling is 3-stream DRAM turnaround (intrinsic to
// the fixed cA||cD output layout).
// 16*4096*128 = 8,388,608 items = 4096 blocks * 256 thr * 8 exactly.

typedef float f32x4 __attribute__((ext_vector_type(4)));

#define B_DIM 16
#define S_DIM 8192
#define C_DIM 512
#define C4 (C_DIM / 4)        // 128 float4 per row
#define SHALF (S_DIM / 2)     // 4096
#define UNROLL 8
#define NTHREADS 256
#define NBLOCKS 4096
#define BLOCK_ITEMS (NTHREADS * UNROLL)   // 2048

__global__ __launch_bounds__(NTHREADS) void wavelet_haar_kernel(
    const f32x4* __restrict__ x, f32x4* __restrict__ out) {
    const float r = 0.70710678118654752440f;

    // i in [0, 2^23): flattened (b, s, c4). Items: i += k*256 -> s += 2k.
    unsigned base = blockIdx.x * BLOCK_ITEMS + threadIdx.x;
    unsigned c4 = base & (C4 - 1);
    unsigned s  = (base >> 7) & (SHALF - 1);
    unsigned b  = base >> 19;

    long inE = ((long)b * S_DIM + 2 * s) * C4 + c4;  // even row, item 0
    long oA  = ((long)b * S_DIM + s) * C4 + c4;      // cA row, item 0
    long oD  = oA + (long)SHALF * C4;                // cD row, item 0
    const long IN_STRIDE  = 4L * C4;   // s += 2 -> even-row float4 idx += 512
    const long OUT_STRIDE = 2L * C4;   // s += 2 -> out float4 idx += 256

    f32x4 e[UNROLL], o[UNROLL];
#pragma unroll
    for (int k = 0; k < UNROLL; ++k) {
        e[k] = __builtin_nontemporal_load(x + inE + k * IN_STRIDE);
        o[k] = __builtin_nontemporal_load(x + inE + k * IN_STRIDE + C4);
    }
#pragma unroll
    for (int k = 0; k < UNROLL; ++k) {
        f32x4 a = (e[k] + o[k]) * r;
        f32x4 d = (e[k] - o[k]) * r;
        __builtin_nontemporal_store(a, out + oA + k * OUT_STRIDE);
        __builtin_nontemporal_store(d, out + oD + k * OUT_STRIDE);
    }
}

extern "C" void kernel_launch(void* const* d_in, const int* in_sizes, int n_in,
                              void* d_out, int out_size, void* d_ws, size_t ws_size,
                              hipStream_t stream) {
    const f32x4* x = (const f32x4*)d_in[0];
    f32x4* out = (f32x4*)d_out;
    wavelet_haar_kernel<<<NBLOCKS, NTHREADS, 0, stream>>>(x, out);
}